// Round 5
// baseline (168.315 us; speedup 1.0000x reference)
//
#include <hip/hip_runtime.h>

// JME Fairness Loss — MI355X, round 5
// Split for attribution + structural cuts:
//   K1 selection_kernel: ONE streaming pass over pred+ts (static-threshold
//       candidate compaction, v>=2.0), LDS radix-select exact top-100
//       threshold, rank-sort, write (key|~idx) per row to ws. Exact radix
//       fallback if static threshold misses (never on this data).
//   K2 expo_kernel: decode ws row, Gumbel noise, soft-rank sigmoid
//       (bit-identical math/order to R4 -> absmax 0.0), accumulate.
//   finalize_kernel unchanged.
// Gumbel = JAX partitionable threefry2x32, key (0,1)  [absmax 0.0 R1/R3/R4]

typedef unsigned int u32;
typedef unsigned long long u64;

__device__ __forceinline__ u32 rotl32(u32 x, int r) { return (x << r) | (x >> (32 - r)); }

__device__ __forceinline__ void tf2x32(u32 k0, u32 k1, u32 x0, u32 x1, u32& o0, u32& o1) {
  u32 ks2 = 0x1BD11BDAu ^ k0 ^ k1;
#define TFR(r) { x0 += x1; x1 = rotl32(x1, r); x1 ^= x0; }
  x0 += k0; x1 += k1;
  TFR(13) TFR(15) TFR(26) TFR(6)
  x0 += k1; x1 += ks2 + 1u;
  TFR(17) TFR(29) TFR(16) TFR(24)
  x0 += ks2; x1 += k0 + 2u;
  TFR(13) TFR(15) TFR(26) TFR(6)
  x0 += k0; x1 += k1 + 3u;
  TFR(17) TFR(29) TFR(16) TFR(24)
  x0 += k1; x1 += ks2 + 4u;
  TFR(13) TFR(15) TFR(26) TFR(6)
  x0 += ks2; x1 += k0 + 5u;
#undef TFR
  o0 = x0; o1 = x1;
}

__device__ __forceinline__ float gumbel_noise(u32 i) {
  u32 o0, o1;
  tf2x32(0u, 1u, 0u, i, o0, o1);
  u32 bits = o0 ^ o1;
  float f = __uint_as_float((bits >> 9) | 0x3f800000u) - 1.0f;  // [0,1)
  const float TINY = 1.17549435e-38f;
  float u = fmaxf(TINY, f + TINY);
  return -logf(-logf(u));
}

__device__ __forceinline__ u32 fkey(float v) {
  u32 u = __float_as_uint(v);
  return u ^ ((u & 0x80000000u) ? 0xFFFFFFFFu : 0x80000000u);  // order-preserving
}

// wave-0 bin selection over hist[256] via shuffle suffix scan.
__device__ __forceinline__ void select_bin(const u32* __restrict__ hist, int shift,
                                           u32* sh_T, u32* sh_A, u32* sh_done,
                                           int lane) {
  u32 prevA = *sh_A;
  u32 target = 100u - prevA;
  u32 c0 = hist[lane * 4 + 0], c1 = hist[lane * 4 + 1];
  u32 c2 = hist[lane * 4 + 2], c3 = hist[lane * 4 + 3];
  u32 s = c0 + c1 + c2 + c3;
  u32 suf = s;
#pragma unroll
  for (int off = 1; off < 64; off <<= 1) {
    u32 o = __shfl_down(suf, off);
    suf += (lane + off < 64) ? o : 0u;
  }
  u32 sufx = suf - s;
  if (sufx < target && suf >= target) {   // exactly one lane
    u32 cc[4] = {c0, c1, c2, c3};
    u32 acc = sufx, bin = 0, cnt = 0;
#pragma unroll
    for (int k = 3; k >= 0; --k) {
      if (acc + cc[k] >= target) { bin = (u32)(lane * 4 + k); cnt = cc[k]; break; }
      acc += cc[k];
    }
    u32 newA = prevA + acc;
    *sh_T = *sh_T | (bin << shift);
    *sh_A = newA;
    *sh_done = (newA + cnt <= 128u || shift == 0) ? 1u : 0u;
  }
}

// ---------------- K1: selection (one block = one row) ----------------
#define KSTAT 0xC0000000u   // fkey(+2.0f): static candidate threshold

__global__ __launch_bounds__(512, 8) void selection_kernel(
    const float* __restrict__ pred,   // [1024][10000]
    const float* __restrict__ ts,     // [1024][10000]
    double* __restrict__ t_sum,
    u64* __restrict__ keyidx_ws) {    // [1024][100]
  const int N4 = 2500, K = 100;
  const int b = blockIdx.x;
  const int t = threadIdx.x;

  __shared__ u64 cand[2048];
  __shared__ u32 hist[256];
  __shared__ u64 sbuf[128];
  __shared__ u64 sorted[128];
  __shared__ u32 rankv[128];
  __shared__ float wred[8];
  __shared__ u32 sh_cnt, sh_nc, sh_T, sh_A, sh_done;

  if (t < 256) hist[t] = 0u;
  if (t < 128) rankv[t] = 0u;
  if (t == 0) { sh_cnt = 0u; sh_nc = 0u; sh_T = 0u; sh_A = 0u; sh_done = 0u; }
  __syncthreads();

  const float4* __restrict__ row4 = (const float4*)(pred + (size_t)b * 10000);
  const float4* __restrict__ tsr4 = (const float4*)(ts + (size_t)b * 10000);

  // ---- single streaming pass: ts sum + static-threshold compaction ----
  float tsum = 0.f;
#pragma unroll
  for (int k = 0; k < 5; ++k) {
    int i4 = t + (k << 9);
    if (k == 4 && i4 >= N4) break;
    float4 pp = row4[i4];
    float4 qq = tsr4[i4];
    tsum += (qq.x + qq.y) + (qq.z + qq.w);
#pragma unroll
    for (int c = 0; c < 4; ++c) {
      float v = (c == 0) ? pp.x : (c == 1) ? pp.y : (c == 2) ? pp.z : pp.w;
      u32 key = fkey(v);
      if (key >= KSTAT) {
        u32 pos = atomicAdd(&sh_cnt, 1u);
        int idx = i4 * 4 + c;
        if (pos < 2048u) cand[pos] = ((u64)key << 32) | (u32)(~(u32)idx);
      }
    }
  }
#pragma unroll
  for (int off = 32; off; off >>= 1) tsum += __shfl_down(tsum, off);
  if ((t & 63) == 0) wred[t >> 6] = tsum;
  __syncthreads();
  if (t == 0) {
    float s8 = 0.f;
#pragma unroll
    for (int w = 0; w < 8; ++w) s8 += wred[w];
    atomicAdd(t_sum, (double)s8);
  }

  u32 cnt_all = sh_cnt;
  bool fast = (cnt_all >= 100u && cnt_all <= 2048u);
  u32 nc = cnt_all < 2048u ? cnt_all : 2048u;

  if (fast) {
    // ---- radix-select exact threshold over LDS candidates ----
    for (int shift = 24; ; shift -= 8) {
      if (t < 256) hist[t] = 0u;
      __syncthreads();
      u32 pref = sh_T >> (shift + 8);  // 0 when shift==24 (sh_T starts 0)
      for (int i = t; i < (int)nc; i += 512) {
        u32 key = (u32)(cand[i] >> 32);
        if (shift == 24 || (key >> (shift + 8)) == pref)
          atomicAdd(&hist[(key >> shift) & 255u], 1u);
      }
      __syncthreads();
      if (t < 64) select_bin(hist, shift, &sh_T, &sh_A, &sh_done, t);
      __syncthreads();
      if (sh_done) break;
    }
    // ---- collect keys >= T from cand ----
    u32 T = sh_T;
    for (int i = t; i < (int)nc; i += 512) {
      u64 p = cand[i];
      if ((u32)(p >> 32) >= T) {
        u32 pos = atomicAdd(&sh_nc, 1u);
        if (pos < 128u) sbuf[pos] = p;
      }
    }
  } else {
    // ---- exact fallback (never hit on this data): global radix ----
    for (int shift = 24; ; shift -= 8) {
      if (t < 256) hist[t] = 0u;
      __syncthreads();
      u32 pref = sh_T >> (shift + 8);
      for (int i4 = t; i4 < N4; i4 += 512) {
        float4 pp = row4[i4];
#pragma unroll
        for (int c = 0; c < 4; ++c) {
          float v = (c == 0) ? pp.x : (c == 1) ? pp.y : (c == 2) ? pp.z : pp.w;
          u32 key = fkey(v);
          if (shift == 24 || (key >> (shift + 8)) == pref)
            atomicAdd(&hist[(key >> shift) & 255u], 1u);
        }
      }
      __syncthreads();
      if (t < 64) select_bin(hist, shift, &sh_T, &sh_A, &sh_done, t);
      __syncthreads();
      if (sh_done) break;
    }
    u32 T = sh_T;
    for (int i4 = t; i4 < N4; i4 += 512) {
      float4 pp = row4[i4];
#pragma unroll
      for (int c = 0; c < 4; ++c) {
        float v = (c == 0) ? pp.x : (c == 1) ? pp.y : (c == 2) ? pp.z : pp.w;
        u32 key = fkey(v);
        if (key >= T) {
          u32 pos = atomicAdd(&sh_nc, 1u);
          int idx = i4 * 4 + c;
          if (pos < 128u) sbuf[pos] = ((u64)key << 32) | (u32)(~(u32)idx);
        }
      }
    }
  }
  __syncthreads();
  u32 nreal = sh_nc < 128u ? sh_nc : 128u;
  if (t < 128 && (u32)t >= nreal) sbuf[t] = 0ull;
  __syncthreads();

  // ---- rank sort 128, descending (u64 keys distinct among real entries) ----
  {
    int e = t >> 2, seg = t & 3;
    u64 mykey = sbuf[e];
    u32 cnt = 0;
    int j0 = seg * 32;
#pragma unroll 8
    for (int j = j0; j < j0 + 32; ++j) cnt += (sbuf[j] > mykey) ? 1u : 0u;
    if (cnt) atomicAdd(&rankv[e], cnt);
    __syncthreads();
    if (t < 128) sorted[rankv[t]] = sbuf[t];
    __syncthreads();
  }

  if (t < K) keyidx_ws[(size_t)b * K + t] = sorted[t];
}

// ---------------- K2: exposure (one block = one row) ----------------
__global__ __launch_bounds__(512, 8) void expo_kernel(
    const u64* __restrict__ keyidx_ws,  // [1024][100]
    const int* __restrict__ ugrp, const int* __restrict__ igrp,
    double* __restrict__ sum_e, double* __restrict__ sum_e2,
    double* __restrict__ pair_sum, int* __restrict__ pair_cnt) {
  const int K = 100;
  const int b = blockIdx.x;
  const int t = threadIdx.x;

  __shared__ float topv[100];
  __shared__ int   pidv[100];
  __shared__ __align__(16) float noisy[1000];   // [10][100]
  __shared__ float expo[100];
  __shared__ float pairS[128];
  __shared__ int   pairC[128];
  __shared__ float sh_bS, sh_bS2;

  if (t < 128) { pairS[t] = 0.f; pairC[t] = 0; }
  if (t < 100) expo[t] = 0.f;
  if (t == 0) { sh_bS = 0.f; sh_bS2 = 0.f; }
  int ug = ugrp[b];
  if (t < K) {
    u64 pk = keyidx_ws[(size_t)b * K + t];
    u32 key = (u32)(pk >> 32);
    u32 idx = ~(u32)pk;
    u32 u = (key & 0x80000000u) ? (key ^ 0x80000000u) : ~key;
    topv[t] = __uint_as_float(u);
    pidv[t] = ug * 16 + igrp[idx];
  }
  __syncthreads();

  // ---- Gumbel noise: 1000 = 10 samples x 100 ----
  for (int si = t; si < 1000; si += 512) {
    int s = si / 100, i = si - s * 100;
    noisy[si] = topv[i] + gumbel_noise(((u32)s * 1024u + (u32)b) * 100u + (u32)i);
  }
  __syncthreads();

  // ---- soft-rank + exposure (bit-identical j-order to R4) ----
  const float C2 = 14.426950408889634f;    // (1/tau) * log2(e)
  const float LG = -0.32192809488736235f;  // log2(0.8)
  for (int si = t; si < 1000; si += 512) {
    int s = si / 100, i = si - s * 100;
    float nvC = noisy[si] * C2;
    const float4* nr4 = (const float4*)(noisy + s * 100);
    float S = 0.f;
#pragma unroll 5
    for (int jc = 0; jc < 25; ++jc) {
      float4 nj = nr4[jc];
      S += __builtin_amdgcn_rcpf(1.0f + exp2f(__builtin_fmaf(nj.x, C2, -nvC)));
      S += __builtin_amdgcn_rcpf(1.0f + exp2f(__builtin_fmaf(nj.y, C2, -nvC)));
      S += __builtin_amdgcn_rcpf(1.0f + exp2f(__builtin_fmaf(nj.z, C2, -nvC)));
      S += __builtin_amdgcn_rcpf(1.0f + exp2f(__builtin_fmaf(nj.w, C2, -nvC)));
    }
    float ex = exp2f((S - 0.5f) * LG);     // gamma^(rank-1)
    atomicAdd(&expo[i], ex);
  }
  __syncthreads();

  // ---- block accumulation ----
  if (t < K) {
    float e = expo[t] * 0.1f;
    atomicAdd(&pairS[pidv[t]], e);
    atomicAdd(&pairC[pidv[t]], 1);
    atomicAdd(&sh_bS, e);
    atomicAdd(&sh_bS2, e * e);
  }
  __syncthreads();
  if (t < 128 && pairC[t] > 0) {
    atomicAdd(&pair_sum[t], (double)pairS[t]);
    atomicAdd(&pair_cnt[t], pairC[t]);
  }
  if (t == 0) {
    atomicAdd(sum_e, (double)sh_bS);
    atomicAdd(sum_e2, (double)sh_bS2);
  }
}

// ---------------- finalize (parallel, 128 thr) ----------------
__global__ __launch_bounds__(128) void finalize_kernel(
    const double* __restrict__ t_sum, const double* __restrict__ sum_e,
    const double* __restrict__ sum_e2, const double* __restrict__ pair_sum,
    const int* __restrict__ pair_cnt, float* __restrict__ out) {
  int t = threadIdx.x;
  __shared__ double red[128];
  double tmean = *t_sum / 10240000.0;
  double g = 0.0;
  int c = pair_cnt[t];
  if (c > 0) {
    double avg = (pair_sum[t] - (double)c * tmean) / (double)c;
    g = avg * avg;
  }
  red[t] = g;
  __syncthreads();
#pragma unroll
  for (int off = 64; off; off >>= 1) {
    if (t < off) red[t] += red[t + off];
    __syncthreads();
  }
  if (t == 0) {
    double gg = red[0] / 128.0;
    double me = *sum_e / 102400.0;
    double me2 = *sum_e2 / 102400.0;
    double ii = me2 - 2.0 * tmean * me + tmean * tmean;
    out[0] = (float)(ii + gg);
    out[1] = (float)ii;
    out[2] = (float)gg;
  }
}

extern "C" void kernel_launch(void* const* d_in, const int* in_sizes, int n_in,
                              void* d_out, int out_size, void* d_ws, size_t ws_size,
                              hipStream_t stream) {
  (void)in_sizes; (void)n_in; (void)out_size; (void)ws_size;
  const float* pred = (const float*)d_in[0];
  const float* ts   = (const float*)d_in[1];
  const int*   ugrp = (const int*)d_in[2];
  const int*   igrp = (const int*)d_in[3];
  float* out = (float*)d_out;

  // ws layout: doubles [t_sum, sum_e, sum_e2, pair_sum[128]] | pair_cnt[128] i32
  //            | keyidx[1024*100] u64
  double* t_sum    = (double*)d_ws;
  double* sum_e    = t_sum + 1;
  double* sum_e2   = t_sum + 2;
  double* pair_sum = t_sum + 3;
  int*    pair_cnt = (int*)(t_sum + 3 + 128);
  u64*    keyidx   = (u64*)((char*)d_ws + (3 + 128) * sizeof(double) + 128 * sizeof(int));

  hipMemsetAsync(d_ws, 0, (3 + 128) * sizeof(double) + 128 * sizeof(int), stream);

  selection_kernel<<<1024, 512, 0, stream>>>(pred, ts, t_sum, keyidx);
  expo_kernel<<<1024, 512, 0, stream>>>(keyidx, ugrp, igrp,
                                        sum_e, sum_e2, pair_sum, pair_cnt);
  finalize_kernel<<<1, 128, 0, stream>>>(t_sum, sum_e, sum_e2, pair_sum, pair_cnt, out);
}